// Round 9
// baseline (557.712 us; speedup 1.0000x reference)
//
#include <hip/hip_runtime.h>
#include <hip/hip_cooperative_groups.h>
#include <cfloat>
#include <cstdint>

namespace cg = cooperative_groups;

// ---------------- problem constants ----------------
#define NC 1536   // 3*H concatenated projection width

// d_out float offsets: emb[16,1024] | out[16] | smiles_attn_pool[16,2048] | seqs_attn_pool[16,128]
#define OUT_EMB 0
#define OUT_OUT 16384
#define OUT_A1  16400
#define OUT_A2  49168

// ws byte offsets
#define WS_NRM_S   0u
#define WS_NRM_M   32768u
#define WS_BCAT    360448u
#define WS_LOG1    366592u
#define WS_PP1     505856u
#define WS_EMB     800768u
#define WS_H1      866304u
#define WS_H2      931840u
#define WS_WCT     1048576u
#define WS_SMISNB  2621440u
#define WS_PSMIS   4718592u
#define WS_SEQSOUT 11010048u
#define WS_SEQSNB  15204352u
#define WS_PSEQS   48758784u
#define WS_SMILOUT WS_SEQSNB          // seqs_nb dead after GEMM1; reuse for smiles_out
// norm partials are consumed before Pseqs is written -> alias that region
#define WS_PART    WS_PSEQS
#define WS_PARTM   (WS_PSEQS + 2097152u)

typedef float f32x4 __attribute__((ext_vector_type(4)));
typedef __bf16 bf16x8 __attribute__((ext_vector_type(8)));
typedef unsigned short u16x8 __attribute__((ext_vector_type(8)));

__device__ __forceinline__ float bf2f(unsigned short h) {
  return __uint_as_float(((unsigned int)h) << 16);
}
__device__ __forceinline__ unsigned short f2bf(float f) {
  unsigned int u = __float_as_uint(f);
  return (unsigned short)((u + 0x7FFFu + ((u >> 16) & 1u)) >> 16);
}
__device__ __forceinline__ void gld16(const unsigned short* g, unsigned short* l) {
  __builtin_amdgcn_global_load_lds(
      (__attribute__((address_space(1))) unsigned int*)(uintptr_t)g,
      (__attribute__((address_space(3))) unsigned int*)l, 16, 0, 0);
}

// position-space mask -> element-space mask for the anti-diagonal transpose layout:
// element 2c sits at position 15-c (low half), element 2c+1 at position 31-c (high half)
__device__ __forceinline__ unsigned pos2elem(unsigned m) {
  unsigned lo = __brev(m & 0xFFFFu) >> 16;   // bit i = m bit (15-i)
  unsigned hi = __brev(m >> 16) >> 16;       // bit i = m bit (31-i)
  lo = (lo | (lo << 8)) & 0x00FF00FFu;
  lo = (lo | (lo << 4)) & 0x0F0F0F0Fu;
  lo = (lo | (lo << 2)) & 0x33333333u;
  lo = (lo | (lo << 1)) & 0x55555555u;
  hi = (hi | (hi << 8)) & 0x00FF00FFu;
  hi = (hi | (hi << 4)) & 0x0F0F0F0Fu;
  hi = (hi | (hi << 2)) & 0x33333333u;
  hi = (hi | (hi << 1)) & 0x55555555u;
  return lo | (hi << 1);
}

#define TRANSPOSE16(B)                                                                             \
  {                                                                                                \
    unsigned t;                                                                                    \
    t = (B[0] ^ (B[8] >> 8)) & 0x00FF00FFu; B[0] ^= t; B[8] ^= (t << 8);                           \
    t = (B[1] ^ (B[9] >> 8)) & 0x00FF00FFu; B[1] ^= t; B[9] ^= (t << 8);                           \
    t = (B[2] ^ (B[10] >> 8)) & 0x00FF00FFu; B[2] ^= t; B[10] ^= (t << 8);                         \
    t = (B[3] ^ (B[11] >> 8)) & 0x00FF00FFu; B[3] ^= t; B[11] ^= (t << 8);                         \
    t = (B[4] ^ (B[12] >> 8)) & 0x00FF00FFu; B[4] ^= t; B[12] ^= (t << 8);                         \
    t = (B[5] ^ (B[13] >> 8)) & 0x00FF00FFu; B[5] ^= t; B[13] ^= (t << 8);                         \
    t = (B[6] ^ (B[14] >> 8)) & 0x00FF00FFu; B[6] ^= t; B[14] ^= (t << 8);                         \
    t = (B[7] ^ (B[15] >> 8)) & 0x00FF00FFu; B[7] ^= t; B[15] ^= (t << 8);                         \
    t = (B[0] ^ (B[4] >> 4)) & 0x0F0F0F0Fu; B[0] ^= t; B[4] ^= (t << 4);                           \
    t = (B[1] ^ (B[5] >> 4)) & 0x0F0F0F0Fu; B[1] ^= t; B[5] ^= (t << 4);                           \
    t = (B[2] ^ (B[6] >> 4)) & 0x0F0F0F0Fu; B[2] ^= t; B[6] ^= (t << 4);                           \
    t = (B[3] ^ (B[7] >> 4)) & 0x0F0F0F0Fu; B[3] ^= t; B[7] ^= (t << 4);                           \
    t = (B[8] ^ (B[12] >> 4)) & 0x0F0F0F0Fu; B[8] ^= t; B[12] ^= (t << 4);                         \
    t = (B[9] ^ (B[13] >> 4)) & 0x0F0F0F0Fu; B[9] ^= t; B[13] ^= (t << 4);                         \
    t = (B[10] ^ (B[14] >> 4)) & 0x0F0F0F0Fu; B[10] ^= t; B[14] ^= (t << 4);                       \
    t = (B[11] ^ (B[15] >> 4)) & 0x0F0F0F0Fu; B[11] ^= t; B[15] ^= (t << 4);                       \
    t = (B[0] ^ (B[2] >> 2)) & 0x33333333u; B[0] ^= t; B[2] ^= (t << 2);                           \
    t = (B[1] ^ (B[3] >> 2)) & 0x33333333u; B[1] ^= t; B[3] ^= (t << 2);                           \
    t = (B[4] ^ (B[6] >> 2)) & 0x33333333u; B[4] ^= t; B[6] ^= (t << 2);                           \
    t = (B[5] ^ (B[7] >> 2)) & 0x33333333u; B[5] ^= t; B[7] ^= (t << 2);                           \
    t = (B[8] ^ (B[10] >> 2)) & 0x33333333u; B[8] ^= t; B[10] ^= (t << 2);                         \
    t = (B[9] ^ (B[11] >> 2)) & 0x33333333u; B[9] ^= t; B[11] ^= (t << 2);                         \
    t = (B[12] ^ (B[14] >> 2)) & 0x33333333u; B[12] ^= t; B[14] ^= (t << 2);                       \
    t = (B[13] ^ (B[15] >> 2)) & 0x33333333u; B[13] ^= t; B[15] ^= (t << 2);                       \
    t = (B[0] ^ (B[1] >> 1)) & 0x55555555u; B[0] ^= t; B[1] ^= (t << 1);                           \
    t = (B[2] ^ (B[3] >> 1)) & 0x55555555u; B[2] ^= t; B[3] ^= (t << 1);                           \
    t = (B[4] ^ (B[5] >> 1)) & 0x55555555u; B[4] ^= t; B[5] ^= (t << 1);                           \
    t = (B[6] ^ (B[7] >> 1)) & 0x55555555u; B[6] ^= t; B[7] ^= (t << 1);                           \
    t = (B[8] ^ (B[9] >> 1)) & 0x55555555u; B[8] ^= t; B[9] ^= (t << 1);                           \
    t = (B[10] ^ (B[11] >> 1)) & 0x55555555u; B[10] ^= t; B[11] ^= (t << 1);                       \
    t = (B[12] ^ (B[13] >> 1)) & 0x55555555u; B[12] ^= t; B[13] ^= (t << 1);                       \
    t = (B[14] ^ (B[15] >> 1)) & 0x55555555u; B[14] ^= t; B[15] ^= (t << 1);                       \
  }

// ---------------- column-wise l2 norms (axis=1), both inputs in one launch ----------------
__global__ __launch_bounds__(128) void knorm_part(const float* __restrict__ seqs, const float* __restrict__ smis,
                                                  float* __restrict__ part_s, float* __restrict__ part_m) {
  int ls = blockIdx.x, b = blockIdx.y, t = threadIdx.x;
  const float* x; float* part; int slab;
  if (ls < 64) { x = seqs; part = part_s + (size_t)(b * 64 + ls) * 512; slab = b * 64 + ls; }
  else { x = smis; part = part_m + (size_t)(b * 4 + (ls - 64)) * 512; slab = b * 4 + (ls - 64); }
  const float* xp = x + (size_t)slab * 32 * 512 + t * 4;
  float ax = 0.f, ay = 0.f, az = 0.f, aw = 0.f;
  for (int l = 0; l < 32; ++l) {
    float4 v = *(const float4*)(xp + (size_t)l * 512);
    ax += v.x * v.x; ay += v.y * v.y; az += v.z * v.z; aw += v.w * v.w;
  }
  float4 r = {ax, ay, az, aw};
  *(float4*)(part + t * 4) = r;
}

// ---------------- merged: knorm_fin (blocks 0-63) + weight prep / bcat / zero-fills (blocks 64+) ----
__global__ __launch_bounds__(256) void kfinprep(const float* __restrict__ part_s, const float* __restrict__ part_m,
                                                float* __restrict__ nrm_s, float* __restrict__ nrm_m,
                                                const float* __restrict__ Wq, const float* __restrict__ Wk,
                                                const float* __restrict__ Wv, unsigned short* __restrict__ WT,
                                                const float* bq, const float* bk, const float* bv,
                                                float* bcat, float* log1, float* h1pre, float* h2pre) {
  __shared__ float T[32][33];
  int t = threadIdx.x;
  if (blockIdx.x < 64) {
    // ---- knorm_fin: bh0<32 seqs (NS=64), else smis (NS=4) ----
    int bh0 = blockIdx.x;
    const float* part; float* inv; int NS, bh;
    if (bh0 < 32) { part = part_s; inv = nrm_s; NS = 64; bh = bh0; }
    else { part = part_m; inv = nrm_m; NS = 4; bh = bh0 - 32; }
    int b = bh >> 1, col = (bh & 1) * 256 + t;
    float s = 0.f;
    for (int j = 0; j < NS; ++j) s += part[((size_t)(b * NS + j)) * 512 + col];
    inv[(size_t)b * 512 + col] = 1.f / fmaxf(sqrtf(s), 1e-12f);
  } else {
    int id = blockIdx.x - 64;
    int m = id >> 8, r256 = id & 255;
    if (m < 3) {
      // ---- WcatT transpose tile ----
      int ti = r256 >> 4, tj = r256 & 15;
      const float* W = m == 0 ? Wq : (m == 1 ? Wk : Wv);
      int c = t & 31, r0 = t >> 5;
#pragma unroll
      for (int j = 0; j < 4; ++j) {
        int r = r0 + j * 8;
        T[r][c] = W[(size_t)(ti * 32 + r) * 512 + tj * 32 + c];
      }
      __syncthreads();
#pragma unroll
      for (int j = 0; j < 4; ++j) {
        int r = r0 + j * 8;
        WT[(size_t)(m * 512 + tj * 32 + r) * 512 + ti * 32 + c] = f2bf(T[c][r]);
      }
    } else {
      // ---- bcat (1536) + zero log1/h1pre/h2pre ----
      int i = r256 * 256 + t;
      if (i < 1536) bcat[i] = i < 512 ? bq[i] : (i < 1024 ? bk[i - 512] : bv[i - 1024]);
      else if (i < 34304) log1[i - 1536] = 0.f;
      else if (i < 50688) h1pre[i - 34304] = 0.f;
      else if (i < 58880) h2pre[i - 50688] = 0.f;
    }
  }
}

// both casts in one launch: blocks [0,16384) seqs, [16384,17408) smis
__global__ __launch_bounds__(256) void kcast(const float* __restrict__ seqs, const float* __restrict__ smis,
                                             const float* __restrict__ nrm_s, const float* __restrict__ nrm_m,
                                             unsigned short* __restrict__ seqs_nb, unsigned short* __restrict__ smis_nb) {
  const float* x; const float* inv; unsigned short* o; int i4, shiftB;
  if (blockIdx.x < 16384) {
    i4 = (blockIdx.x * 256 + threadIdx.x) * 4; x = seqs; inv = nrm_s; o = seqs_nb; shiftB = 20;
  } else {
    i4 = ((blockIdx.x - 16384) * 256 + threadIdx.x) * 4; x = smis; inv = nrm_m; o = smis_nb; shiftB = 16;
  }
  int b = i4 >> shiftB;
  float4 v = *(const float4*)(x + i4);
  float4 nv = *(const float4*)(inv + (b << 9) + (i4 & 511));
  ushort4 r;
  r.x = f2bf(v.x * nv.x); r.y = f2bf(v.y * nv.y);
  r.z = f2bf(v.z * nv.z); r.w = f2bf(v.w * nv.w);
  *(ushort4*)(o + i4) = r;
}

// ---------------- bf16 MFMA GEMM: C[M,N] = A[M,K] @ Bt[N,K]^T + bias ----------------
// v3 + merged big/small dispatch. LDS dbuf (1 barrier/K-iter) + XCD remap. Single dispatch.
__global__ __launch_bounds__(256) void kgemm(const unsigned short* __restrict__ A1,
                                             const unsigned short* __restrict__ A2,
                                             const unsigned short* __restrict__ Bt,
                                             const float* __restrict__ bias,
                                             unsigned short* __restrict__ C1,
                                             unsigned short* __restrict__ C2) {
  const int K = 512, N = NC, NT = 12;
  __shared__ unsigned short As[2][128 * 32], Bs[2][128 * 32];
  int tid = threadIdx.x, lane = tid & 63, wave = tid >> 6;
  int id = blockIdx.x;
  const unsigned short* A; unsigned short* C;
  if (id < 3072) { A = A1; C = C1; }
  else { A = A2; C = C2; id -= 3072; }
  int xcd = id & 7, j = id >> 3;
  int mloc = j / NT, n = j - mloc * NT;
  int m0 = (mloc * 8 + xcd) * 128, n0 = n * 128;
  f32x4 acc[4][4] = {};
  int wm = (wave >> 1) * 64, wn = (wave & 1) * 64;
  int frow = lane & 15, fk = (lane >> 4) * 8;

  auto stage = [&](int buf, int k0) {
#pragma unroll
    for (int jj = 0; jj < 2; ++jj) {
      int ch = jj * 256 + tid;
      int row = ch >> 2, kc = (ch & 3) * 8;
      gld16(A + (size_t)(m0 + row) * K + k0 + kc, As[buf] + ch * 8);
      gld16(Bt + (size_t)(n0 + row) * K + k0 + kc, Bs[buf] + ch * 8);
    }
  };

  stage(0, 0);
  __syncthreads();
  int nk = K >> 5;
  for (int it = 0; it < nk; ++it) {
    int cur = it & 1;
    if (it + 1 < nk) stage(cur ^ 1, (it + 1) << 5);
    bf16x8 af[4], bfv[4];
#pragma unroll
    for (int mt = 0; mt < 4; ++mt) af[mt] = *(const bf16x8*)&As[cur][(wm + mt * 16 + frow) * 32 + fk];
#pragma unroll
    for (int nt = 0; nt < 4; ++nt) bfv[nt] = *(const bf16x8*)&Bs[cur][(wn + nt * 16 + frow) * 32 + fk];
#pragma unroll
    for (int mt = 0; mt < 4; ++mt)
#pragma unroll
      for (int nt = 0; nt < 4; ++nt)
        acc[mt][nt] = __builtin_amdgcn_mfma_f32_16x16x32_bf16(af[mt], bfv[nt], acc[mt][nt], 0, 0, 0);
    __syncthreads();
  }
  int q = lane >> 4, c15 = lane & 15;
#pragma unroll
  for (int mt = 0; mt < 4; ++mt)
#pragma unroll
    for (int nt = 0; nt < 4; ++nt) {
      int col = n0 + wn + nt * 16 + c15;
      float bv = bias[col];
#pragma unroll
      for (int r = 0; r < 4; ++r) {
        int row = m0 + wm + mt * 16 + q * 4 + r;
        C[(size_t)row * N + col] = f2bf(acc[mt][nt][r] + bv);
      }
    }
}

// ---------------- fusion 1: Q=seqs(2048) K,V=smis(128); top-32 of 128 ----------------
// v5 dense writeback (R5 lesson: divergent sparse while-loop regressed). Single dispatch.
__global__ __launch_bounds__(256) void kfusion1(const unsigned short* __restrict__ Pseqs,
                                                const unsigned short* __restrict__ Psmis,
                                                const float* __restrict__ wp,
                                                unsigned short* __restrict__ smil,
                                                float* __restrict__ logits) {
  constexpr int PP = 136;                 // halfword pitch, rows 16B-aligned
  __shared__ unsigned short Sc[64 * PP];  // scores, then unnormalized P (bf16)
  __shared__ unsigned short Vt[64 * PP];  // V^T [e][s ^ (e&56)] (swizzled)
  int tid = threadIdx.x, lane = tid & 63, w = tid >> 6;
  int lt = blockIdx.x, h = blockIdx.y, b = blockIdx.z;
  int l0 = lt * 64;
  int frow = lane & 15, q = lane >> 4, fk8 = q * 8;

  // stage V^T, XOR swizzle on s-blocks
  for (int ch = tid; ch < 1024; ch += 256) {
    int s = ch >> 3, e8 = (ch & 7) * 8;
    u16x8 vv = *(const u16x8*)&Psmis[(size_t)(b * 128 + s) * NC + 1024 + h * 64 + e8];
#pragma unroll
    for (int j = 0; j < 8; ++j) {
      int e = e8 + j;
      Vt[e * PP + (s ^ (e & 56))] = vv[j];
    }
  }

  // scores: wave w's 16 Q-rows x 128 keys, fragments from global (L2-hot)
  {
    f32x4 acc[8] = {};
    const unsigned short* qrow = Pseqs + (size_t)(b * 2048 + l0 + w * 16 + frow) * NC + h * 64 + fk8;
#pragma unroll
    for (int ks = 0; ks < 2; ++ks) {
      bf16x8 a = *(const bf16x8*)(qrow + ks * 32);
#pragma unroll
      for (int nt = 0; nt < 8; ++nt) {
        bf16x8 bb = *(const bf16x8*)&Psmis[(size_t)(b * 128 + nt * 16 + frow) * NC + 512 + h * 64 + ks * 32 + fk8];
        acc[nt] = __builtin_amdgcn_mfma_f32_16x16x32_bf16(a, bb, acc[nt], 0, 0, 0);
      }
    }
#pragma unroll
    for (int nt = 0; nt < 8; ++nt)
#pragma unroll
      for (int r = 0; r < 4; ++r)
        Sc[(w * 16 + q * 4 + r) * PP + nt * 16 + frow] = f2bf(acc[nt][r]);
  }
  __syncthreads();

  // selection: lane owns 32 cols (seg = lane&3) of row (lane>>2); 16 rows per wave in one pass
  {
    int i = lane >> 2, seg = lane & 3;
    int row = w * 16 + i;
    unsigned short* rb = &Sc[row * PP + seg * 32];
    unsigned orig[16], B[16];
#pragma unroll
    for (int jb = 0; jb < 4; ++jb) {
      uint4 qv = *(const uint4*)(rb + jb * 8);
      orig[jb * 4 + 0] = qv.x; orig[jb * 4 + 1] = qv.y;
      orig[jb * 4 + 2] = qv.z; orig[jb * 4 + 3] = qv.w;
    }
#pragma unroll
    for (int j = 0; j < 16; ++j) {
      unsigned s = (orig[j] >> 15) & 0x00010001u;
      B[j] = orig[j] ^ (s * 0x7FFFu) ^ 0x80008000u;
    }
    TRANSPOSE16(B)
    unsigned act = 0xFFFFFFFFu, gt = 0u, Tv = 0u;
    int rem = 32;
#pragma unroll
    for (int bit = 15; bit >= 0; --bit) {
      unsigned bm = B[15 - bit] & act;
      int c = __popc(bm);
      c += __shfl_xor(c, 1);
      c += __shfl_xor(c, 2);
      bool take = (c >= rem);
      act = take ? bm : (act ^ bm);
      gt = take ? gt : (gt | bm);
      rem = take ? rem : (rem - c);
      Tv = take ? (Tv | (1u << bit)) : Tv;
    }
    unsigned hT = (Tv & 0x8000u) ? (Tv ^ 0x8000u) : (Tv ^ 0xFFFFu);
    float vT = bf2f((unsigned short)hT);
    unsigned gtE = pos2elem(gt), actE = pos2elem(act);
    int pc = __popc(actE);
    int pr1 = __shfl_up(pc, 1);
    int inc = pc + ((seg >= 1) ? pr1 : 0);
    int pr2 = __shfl_up(inc, 2);
    inc += ((seg >= 2) ? pr2 : 0);
    int tie_pre = inc - pc;
    int budget = rem - tie_pre;
    budget = budget < 0 ? 0 : (budget > pc ? pc : budget);
    unsigned selT = 0u, m = actE;
    for (int t = 0; t < budget; ++t) { unsigned bb2 = m & (~m + 1u); selT |= bb2; m ^= bb2; }
    unsigned sel = gtE | selT;
    unsigned* wb = (unsigned*)rb;
#pragma unroll
    for (int j = 0; j < 16; ++j) {
      unsigned d = orig[j];
      float v0 = bf2f((unsigned short)(d & 0xFFFFu));
      float v1 = bf2f((unsigned short)(d >> 16));
      float e0 = ((sel >> (2 * j)) & 1u) ? __expf((v0 - vT) * 0.125f) : 0.f;
      float e1 = ((sel >> (2 * j + 1)) & 1u) ? __expf((v1 - vT) * 0.125f) : 0.f;
      wb[j] = (unsigned)f2bf(e0) | ((unsigned)f2bf(e1) << 16);
    }
  }
  __syncthreads();

  // O_un = P_un[16x128] @ V[128x64]; den = P_un @ ones (extra MFMA column)
  f32x4 oacc[4] = {};
  f32x4 dacc = {};
  bf16x8 ones;
#pragma unroll
  for (int j = 0; j < 8; ++j) ones[j] = (__bf16)1.0f;
#pragma unroll
  for (int k0 = 0; k0 < 128; k0 += 32) {
    bf16x8 a = *(const bf16x8*)&Sc[(w * 16 + frow) * PP + k0 + fk8];
#pragma unroll
    for (int nt = 0; nt < 4; ++nt) {
      int e = nt * 16 + frow;
      bf16x8 bb = *(const bf16x8*)&Vt[e * PP + ((k0 + fk8) ^ (e & 56))];
      oacc[nt] = __builtin_amdgcn_mfma_f32_16x16x32_bf16(a, bb, oacc[nt], 0, 0, 0);
    }
    dacc = __builtin_amdgcn_mfma_f32_16x16x32_bf16(a, ones, dacc, 0, 0, 0);
  }
  float inv4[4];
#pragma unroll
  for (int r = 0; r < 4; ++r) inv4[r] = 1.f / dacc[r];
  // write O and accumulate pool-1 logit partials
  float wv[4];
#pragma unroll
  for (int nt = 0; nt < 4; ++nt) wv[nt] = wp[h * 64 + nt * 16 + frow];
  float lg[4];
#pragma unroll
  for (int r = 0; r < 4; ++r) lg[r] = 0.f;
#pragma unroll
  for (int nt = 0; nt < 4; ++nt)
#pragma unroll
    for (int r = 0; r < 4; ++r) {
      float ov = oacc[nt][r] * inv4[r];
      smil[(size_t)(b * 2048 + l0 + w * 16 + q * 4 + r) * 512 + h * 64 + nt * 16 + frow] = f2bf(ov);
      lg[r] += ov * wv[nt];
    }
#pragma unroll
  for (int d = 1; d < 16; d <<= 1)
#pragma unroll
    for (int r = 0; r < 4; ++r) lg[r] += __shfl_xor(lg[r], d);
  if (frow == 0) {
#pragma unroll
    for (int r = 0; r < 4; ++r)
      atomicAdd(&logits[b * 2048 + l0 + w * 16 + q * 4 + r], lg[r]);
  }
}

// ---------------- fusion 2 + pool1b MERGED (R9) ----------------
// Blocks [0,1024): kf2fused v3 (flattened grid, bh-major preserved: bh=bid&127, rt=bid>>7).
// Blocks [1024,1280): kpool1b rewritten for 1024 threads; scratch aliased into S.
// The two halves have disjoint dependencies (kgemm vs kfusion1) -> merging hides pool1b's
// ~8us under kf2fused and saves one dispatch (~8us measured overhead/dispatch, R8).
__global__ __launch_bounds__(1024, 8) void kf2pool(const unsigned short* __restrict__ Psmis,
                                                   const unsigned short* __restrict__ Pseqs,
                                                   float* __restrict__ seqs_out,
                                                   const unsigned short* __restrict__ xsm,
                                                   const float* __restrict__ logits,
                                                   float* __restrict__ aout, float* __restrict__ pp) {
  __shared__ unsigned short S[16 * 2048];  // 64 KB: bf16 scores (kf2) / float scratch (pool1b)
  __shared__ float pS[16][32];
  __shared__ int   sS[16][32];
  int tid = threadIdx.x, lane = tid & 63, w = tid >> 6;  // w in 0..15

  if (blockIdx.x >= 1024) {
    // ======== pool1b path (256 blocks, 1024 threads) ========
    int bid = blockIdx.x - 1024;
    int b = bid >> 4, ls = (bid >> 1) & 7, cj = bid & 1;
    float* redf = (float*)S;           // 1024 floats, bytes [0,4096)
    float* aSf = (float*)(S + 2048);   // 256 floats, bytes [4096,5120)
    const float* lg = logits + b * 2048;
    int t = tid;
    float lm = fmaxf(lg[t], lg[t + 1024]);
    redf[t] = lm; __syncthreads();
    for (int s = 512; s > 0; s >>= 1) { if (t < s) redf[t] = fmaxf(redf[t], redf[t + s]); __syncthreads(); }
    float M = redf[0]; __syncthreads();
    float sm = __expf(lg[t] - M) + __expf(lg[t + 1024] - M);
    redf[t] = sm; __syncthreads();
    for (int s = 512; s > 0; s >>= 1) { if (t < s) redf[t] += redf[t + s]; __syncthreads(); }
    float D = redf[0]; __syncthreads();
    int l0 = ls * 256;
    int tc = t & 255, g = t >> 8;
    if (g == 0) {
      float a = __expf(lg[l0 + tc] - M) / D;
      aSf[tc] = a;
      if (cj == 0) aout[b * 2048 + l0 + tc] = a;
    }
    __syncthreads();
    int col = cj * 256 + tc;
    float acc0 = 0.f;
    const unsigned short* xb = xsm + ((size_t)b * 2048 + l0 + g * 64) * 512 + col;
#pragma unroll 8
    for (int ll = 0; ll < 64; ++ll) acc0 += aSf[g * 64 + ll] * bf2f(xb[(size_t)ll * 512]);
    redf[t] = acc0; __syncthreads();
    if (g == 0)
      pp[(size_t)(b * 8 + ls) * 512 + col] = redf[tc] + redf[256 + tc] + redf[512 + tc] + redf[768 + tc];
    return;
  }

  // ======== kf2fused path (1024 blocks) ========
  int bh = blockIdx.x & 127, rt = blockIdx.x >> 7;
  int b = bh >> 3, h = bh & 7;
  int frow = lane & 15, q = lane >> 4, fk8 = q * 8;

  // ---- scores: rows l = rt*16..+15 (smis queries); wave w covers s in [w*128,(w+1)*128) ----
  {
    const unsigned short* qrow = Psmis + (size_t)(b * 128 + rt * 16 + frow) * NC + h * 64 + fk8;
    bf16x8 a0 = *(const bf16x8*)qrow;
    bf16x8 a1 = *(const bf16x8*)(qrow + 32);
    const unsigned short* Bb = Pseqs + (size_t)(b * 2048) * NC + 512 + h * 64 + fk8;
#pragma unroll
    for (int nt = 0; nt < 8; ++nt) {
      int n0 = w * 128 + nt * 16;
      const unsigned short* brow = Bb + (size_t)(n0 + frow) * NC;
      bf16x8 b0 = *(const bf16x8*)brow;
      bf16x8 b1 = *(const bf16x8*)(brow + 32);
      f32x4 acc = {};
      acc = __builtin_amdgcn_mfma_f32_16x16x32_bf16(a0, b0, acc, 0, 0, 0);
      acc = __builtin_amdgcn_mfma_f32_16x16x32_bf16(a1, b1, acc, 0, 0, 0);
      int el = n0 + frow;
      int cc = el >> 3;
      int base = cc ^ ((cc >> 3) & 7);
#pragma unroll
      for (int r = 0; r < 4; ++r) {
        int row = q * 4 + r;
        S[row * 2048 + ((base ^ (row & 7)) << 3) + (el & 7)] = f2bf(acc[r]);
      }
    }
  }
  __syncthreads();

  // ---- per-wave selection: wave w owns row w ----
  int lr = w, x = w & 7;

  unsigned B[16];
  {
    const uint4* p4 = (const uint4*)&S[lr * 2048];
#pragma unroll
    for (int i = 0; i < 4; ++i) {
      int cc = lane * 4 + i;
      int base = cc ^ ((cc >> 3) & 7);
      uint4 qa = p4[base ^ x];
      B[i * 4 + 0] = qa.x; B[i * 4 + 1] = qa.y; B[i * 4 + 2] = qa.z; B[i * 4 + 3] = qa.w;
    }
  }
#pragma unroll
  for (int i = 0; i < 16; ++i) {
    unsigned s0 = (B[i] >> 15) & 0x00010001u;
    B[i] = B[i] ^ (s0 * 0x7FFFu) ^ 0x80008000u;
  }
  TRANSPOSE16(B)
  unsigned act = 0xFFFFFFFFu, gt = 0u, Tv = 0u;
  int rem = 32;
#pragma unroll
  for (int bit = 15; bit >= 0; --bit) {
    unsigned bm = B[15 - bit] & act;
    int c = __popc(bm);
#pragma unroll
    for (int d = 1; d < 64; d <<= 1) c += __shfl_xor(c, d);
    bool take = (c >= rem);
    unsigned actx = act ^ bm;
    act = take ? bm : actx;
    gt = take ? gt : (gt | bm);
    rem = take ? rem : (rem - c);
    Tv = take ? (Tv | (1u << bit)) : Tv;
  }
  unsigned hT = (Tv & 0x8000u) ? (Tv ^ 0x8000u) : (Tv ^ 0xFFFFu);
  float vT = bf2f((unsigned short)hT);

  gt = pos2elem(gt);
  act = pos2elem(act);

  int pc_tie = __popc(act);
  int inc = pc_tie;
#pragma unroll
  for (int d = 1; d < 64; d <<= 1) { int y = __shfl_up(inc, d); if (lane >= d) inc += y; }
  int tie_pre = inc - pc_tie;
  int budget = rem - tie_pre;
  budget = budget < 0 ? 0 : (budget > pc_tie ? pc_tie : budget);
  int total_lane = __popc(gt) + budget;
  int inc2 = total_lane;
#pragma unroll
  for (int d = 1; d < 64; d <<= 1) { int y = __shfl_up(inc2, d); if (lane >= d) inc2 += y; }
  int slot = inc2 - total_lane;

  float lsum = 0.f;
  {
    unsigned m = gt;
    while (m) {
      int e = __builtin_ctz(m); m &= m - 1;
      int gidx = (lane << 5) + e;
      int cc = gidx >> 3;
      float v = bf2f(S[lr * 2048 + (((cc ^ ((cc >> 3) & 7)) ^ x) << 3) + (gidx & 7)]);
      float ev = __expf((v - vT) * 0.125f);
      pS[lr][slot] = ev; sS[lr][slot] = gidx; ++slot; lsum += ev;
    }
    m = act;
    for (int taken = 0; taken < budget; ++taken) {
      int e = __builtin_ctz(m); m &= m - 1;
      int gidx = (lane << 5) + e;
      int cc = gidx >> 3;
      float v = bf2f(S[lr * 2048 + (((cc ^ ((cc >> 3) & 7)) ^ x) << 3) + (gidx & 7)]);
      float ev = __expf((v - vT) * 0.125f);
      pS[lr][slot] = ev; sS[lr][slot] = gidx; ++slot; lsum += ev;
    }
  }
  float den = lsum;
#pragma unroll
  for (int d = 1; d < 64; d <<= 1) den += __shfl_xor(den, d);

  // ---- PV gather ----
  float acc = 0.f;
  const unsigned short* Vb = Pseqs + (size_t)(b * 2048) * NC + 1024 + h * 64 + lane;
#pragma unroll 8
  for (int t = 0; t < 32; ++t) {
    acc += pS[lr][t] * bf2f(Vb[(size_t)sS[lr][t] * NC]);
  }
  seqs_out[(size_t)(b * 128 + rt * 16 + lr) * 512 + h * 64 + lane] = acc / den;
}

// ---------------- head COOPERATIVE (R9): pool2emb + kh1 + kh2 + kout in one launch ----------------
// Chain of 4 tiny kernels was 4 dispatches (~32us overhead for ~15us work). One cooperative
// launch (grid 256 x 256 threads, 1 block/CU -- trivially co-resident) with grid.sync()
// between phases. __threadfence() before each sync for cross-XCD visibility.
__global__ __launch_bounds__(256) void khead(const float* __restrict__ x,
                                             const float* __restrict__ wp, const float* __restrict__ bp,
                                             const float* __restrict__ pp,
                                             float* __restrict__ a2out, float* __restrict__ embo,
                                             const float* __restrict__ W1, const float* __restrict__ b1,
                                             float* __restrict__ h1pre,
                                             const float* __restrict__ W2, const float* __restrict__ b2,
                                             float* __restrict__ h2pre,
                                             const float* __restrict__ W3, const float* __restrict__ b3,
                                             float* __restrict__ outp) {
  cg::grid_group grid = cg::this_grid();
  __shared__ float lgS[128];
  __shared__ float red[256];
  __shared__ float eS[4][64];
  int t = threadIdx.x, bid = blockIdx.x;

  // ---- phase 1: pool2emb (blocks 0..15) ----
  if (bid < 16) {
    int lane = t & 63, wave = t >> 6, b = bid;
    for (int i = 0; i < 32; ++i) {
      int row = wave * 32 + i;
      const float* xp = x + (size_t)(b * 128 + row) * 512;
      float acc = 0.f;
#pragma unroll
      for (int j = 0; j < 8; ++j) acc += xp[lane + 64 * j] * wp[lane + 64 * j];
#pragma unroll
      for (int d = 1; d < 64; d <<= 1) acc += __shfl_xor(acc, d);
      if (lane == 0) lgS[row] = acc + bp[0];
    }
    __syncthreads();
    if (wave == 0) {
      float a0 = lgS[lane], a1 = lgS[64 + lane];
      float m = fmaxf(a0, a1);
#pragma unroll
      for (int d = 1; d < 64; d <<= 1) m = fmaxf(m, __shfl_xor(m, d));
      float e0 = __expf(a0 - m), e1 = __expf(a1 - m);
      float sden = e0 + e1;
#pragma unroll
      for (int d = 1; d < 64; d <<= 1) sden += __shfl_xor(sden, d);
      a0 = e0 / sden; a1 = e1 / sden;
      lgS[lane] = a0; lgS[64 + lane] = a1;
      a2out[b * 128 + lane] = a0;
      a2out[b * 128 + 64 + lane] = a1;
    }
    __syncthreads();
    float acc0 = 0.f, acc1 = 0.f;
#pragma unroll 4
    for (int row = 0; row < 128; ++row) {
      float av = lgS[row];
      const float* xp = x + (size_t)(b * 128 + row) * 512;
      acc0 += av * xp[t];
      acc1 += av * xp[t + 256];
    }
    float pre0 = 0.f, pre1 = 0.f;
    for (int lsl = 0; lsl < 8; ++lsl) {
      pre0 += pp[(size_t)(b * 8 + lsl) * 512 + t];
      pre1 += pp[(size_t)(b * 8 + lsl) * 512 + 256 + t];
    }
    float ssq = pre0 * pre0 + pre1 * pre1 + acc0 * acc0 + acc1 * acc1;
    red[t] = ssq; __syncthreads();
    for (int s2 = 128; s2 > 0; s2 >>= 1) { if (t < s2) red[t] += red[t + s2]; __syncthreads(); }
    float inv = 1.f / fmaxf(sqrtf(red[0]), 1e-12f);
    embo[(size_t)b * 1024 + t] = pre0 * inv;
    embo[(size_t)b * 1024 + 256 + t] = pre1 * inv;
    embo[(size_t)b * 1024 + 512 + t] = acc0 * inv;
    embo[(size_t)b * 1024 + 768 + t] = acc1 * inv;
  }
  __threadfence();
  grid.sync();

  // ---- phase 2: kh1 (all 256 blocks): h1pre += emb-chunk @ W1-chunk ----
  {
    int jc = bid & 3, bg = (bid >> 2) & 3, kc = bid >> 4;
    int j = jc * 256 + t, b0 = bg * 4, i0 = kc * 64;
    eS[t >> 6][t & 63] = embo[(size_t)(b0 + (t >> 6)) * 1024 + i0 + (t & 63)];
    __syncthreads();
    float a0 = 0.f, a1 = 0.f, a2 = 0.f, a3 = 0.f;
#pragma unroll 8
    for (int i = 0; i < 64; ++i) {
      float wv = W1[(size_t)(i0 + i) * 1024 + j];
      a0 += eS[0][i] * wv; a1 += eS[1][i] * wv; a2 += eS[2][i] * wv; a3 += eS[3][i] * wv;
    }
    atomicAdd(&h1pre[(b0 + 0) * 1024 + j], a0);
    atomicAdd(&h1pre[(b0 + 1) * 1024 + j], a1);
    atomicAdd(&h1pre[(b0 + 2) * 1024 + j], a2);
    atomicAdd(&h1pre[(b0 + 3) * 1024 + j], a3);
  }
  __threadfence();
  grid.sync();

  // ---- phase 3: kh2 (blocks 0..127): h2pre += relu(h1pre+b1)-chunk @ W2-chunk ----
  if (bid < 128) {
    int jc = bid & 1, bg = (bid >> 1) & 3, kc = bid >> 3;
    int j = jc * 256 + t, b0 = bg * 4, i0 = kc * 64;
    eS[t >> 6][t & 63] = fmaxf(h1pre[(size_t)(b0 + (t >> 6)) * 1024 + i0 + (t & 63)] + b1[i0 + (t & 63)], 0.f);
    __syncthreads();
    float a0 = 0.f, a1 = 0.f, a2 = 0.f, a3 = 0.f;
#pragma unroll 8
    for (int i = 0; i < 64; ++i) {
      float wv = W2[(size_t)(i0 + i) * 512 + j];
      a0 += eS[0][i] * wv; a1 += eS[1][i] * wv; a2 += eS[2][i] * wv; a3 += eS[3][i] * wv;
    }
    atomicAdd(&h2pre[(b0 + 0) * 512 + j], a0);
    atomicAdd(&h2pre[(b0 + 1) * 512 + j], a1);
    atomicAdd(&h2pre[(b0 + 2) * 512 + j], a2);
    atomicAdd(&h2pre[(b0 + 3) * 512 + j], a3);
  }
  __threadfence();
  grid.sync();

  // ---- phase 4: kout (blocks 0..15) ----
  if (bid < 16) {
    int b = bid;
    float acc = 0.f;
    for (int j = t; j < 512; j += 256)
      acc += fmaxf(h2pre[b * 512 + j] + b2[j], 0.f) * W3[j];
    red[t] = acc; __syncthreads();
    for (int s = 128; s > 0; s >>= 1) { if (t < s) red[t] += red[t + s]; __syncthreads(); }
    if (t == 0) outp[b] = red[0] + b3[0];
  }
}

// ---------------- launch ----------------
extern "C" void kernel_launch(void* const* d_in, const int* in_sizes, int n_in,
                              void* d_out, int out_size, void* d_ws, size_t ws_size,
                              hipStream_t stream) {
  const float* seqs = (const float*)d_in[0];
  const float* smis = (const float*)d_in[1];
  const float* Wq = (const float*)d_in[2];
  const float* bq = (const float*)d_in[3];
  const float* Wk = (const float*)d_in[4];
  const float* bk = (const float*)d_in[5];
  const float* Wv = (const float*)d_in[6];
  const float* bv = (const float*)d_in[7];
  const float* wp = (const float*)d_in[8];
  const float* bp = (const float*)d_in[9];
  const float* W1 = (const float*)d_in[10];
  const float* b1 = (const float*)d_in[11];
  const float* W2 = (const float*)d_in[12];
  const float* b2 = (const float*)d_in[13];
  const float* W3 = (const float*)d_in[14];
  const float* b3 = (const float*)d_in[15];
  float* out = (float*)d_out;
  char* ws = (char*)d_ws;

  float* nrm_s = (float*)(ws + WS_NRM_S);
  float* nrm_m = (float*)(ws + WS_NRM_M);
  float* part_s = (float*)(ws + WS_PART);
  float* part_m = (float*)(ws + WS_PARTM);
  float* bcat = (float*)(ws + WS_BCAT);
  float* log1 = (float*)(ws + WS_LOG1);
  float* pp1 = (float*)(ws + WS_PP1);
  float* h1pre = (float*)(ws + WS_H1);
  float* h2pre = (float*)(ws + WS_H2);
  unsigned short* wct = (unsigned short*)(ws + WS_WCT);
  unsigned short* smis_nb = (unsigned short*)(ws + WS_SMISNB);
  unsigned short* Psmis = (unsigned short*)(ws + WS_PSMIS);
  float* seqs_out = (float*)(ws + WS_SEQSOUT);
  unsigned short* seqs_nb = (unsigned short*)(ws + WS_SEQSNB);
  unsigned short* Pseqs = (unsigned short*)(ws + WS_PSEQS);
  unsigned short* smil = (unsigned short*)(ws + WS_SMILOUT);

  // 1. column norms (part buffers alias Pseqs region; consumed before kgemm writes it)
  knorm_part<<<dim3(68, 16), 128, 0, stream>>>(seqs, smis, part_s, part_m);
  // 2. norm finalize + weight prep + bcat + zero-fills (merged)
  kfinprep<<<dim3(1088), 256, 0, stream>>>(part_s, part_m, nrm_s, nrm_m,
                                           Wq, Wk, Wv, wct, bq, bk, bv, bcat, log1, h1pre, h2pre);
  // 3. normalize + cast to bf16 (both inputs)
  kcast<<<dim3(17408), 256, 0, stream>>>(seqs, smis, nrm_s, nrm_m, seqs_nb, smis_nb);
  // 4. fused QKV projections
  kgemm<<<dim3(3264), 256, 0, stream>>>(seqs_nb, smis_nb, wct, bcat, Pseqs, Psmis);
  // 5. fusion 1 attention + fused pool-1 logits
  kfusion1<<<dim3(32, 8, 16), 256, 0, stream>>>(Pseqs, Psmis, wp, smil, log1);
  // 6. fusion 2 + pool 1 merged (disjoint deps -> concurrent in one dispatch)
  kf2pool<<<dim3(1280), 1024, 0, stream>>>(Psmis, Pseqs, seqs_out, smil, log1, out + OUT_A1, pp1);
  // 7. head: pool2emb + MLP chain in ONE cooperative launch (3 fewer dispatches)
  {
    float* a2outp = out + OUT_A2;
    float* embop = out + OUT_EMB;
    float* outp = out + OUT_OUT;
    void* args[] = {(void*)&seqs_out, (void*)&wp, (void*)&bp, (void*)&pp1,
                    (void*)&a2outp, (void*)&embop,
                    (void*)&W1, (void*)&b1, (void*)&h1pre,
                    (void*)&W2, (void*)&b2, (void*)&h2pre,
                    (void*)&W3, (void*)&b3, (void*)&outp};
    hipLaunchCooperativeKernel((const void*)khead, dim3(256), dim3(256), args, 0, stream);
  }
}

// Round 10
// 382.164 us; speedup vs baseline: 1.4594x; 1.4594x over previous
//
#include <hip/hip_runtime.h>
#include <cfloat>
#include <cstdint>

// ---------------- problem constants ----------------
#define NC 1536   // 3*H concatenated projection width

// d_out float offsets: emb[16,1024] | out[16] | smiles_attn_pool[16,2048] | seqs_attn_pool[16,128]
#define OUT_EMB 0
#define OUT_OUT 16384
#define OUT_A1  16400
#define OUT_A2  49168

// ws byte offsets
#define WS_NRM_S   0u
#define WS_NRM_M   32768u
#define WS_BCAT    360448u
#define WS_LOG1    366592u
#define WS_PP1     505856u
#define WS_EMB     800768u
#define WS_H1      866304u
#define WS_H2      931840u
#define WS_WCT     1048576u
#define WS_SMISNB  2621440u
#define WS_PSMIS   4718592u
#define WS_SEQSOUT 11010048u
#define WS_SEQSNB  15204352u
#define WS_PSEQS   48758784u
#define WS_SMILOUT WS_SEQSNB          // seqs_nb dead after GEMM1; reuse for smiles_out
// norm partials are consumed before Pseqs is written -> alias that region
#define WS_PART    WS_PSEQS
#define WS_PARTM   (WS_PSEQS + 2097152u)

typedef float f32x4 __attribute__((ext_vector_type(4)));
typedef __bf16 bf16x8 __attribute__((ext_vector_type(8)));
typedef unsigned short u16x8 __attribute__((ext_vector_type(8)));

__device__ __forceinline__ float bf2f(unsigned short h) {
  return __uint_as_float(((unsigned int)h) << 16);
}
__device__ __forceinline__ unsigned short f2bf(float f) {
  unsigned int u = __float_as_uint(f);
  return (unsigned short)((u + 0x7FFFu + ((u >> 16) & 1u)) >> 16);
}
__device__ __forceinline__ void gld16(const unsigned short* g, unsigned short* l) {
  __builtin_amdgcn_global_load_lds(
      (__attribute__((address_space(1))) unsigned int*)(uintptr_t)g,
      (__attribute__((address_space(3))) unsigned int*)l, 16, 0, 0);
}

// position-space mask -> element-space mask for the anti-diagonal transpose layout:
// element 2c sits at position 15-c (low half), element 2c+1 at position 31-c (high half)
__device__ __forceinline__ unsigned pos2elem(unsigned m) {
  unsigned lo = __brev(m & 0xFFFFu) >> 16;   // bit i = m bit (15-i)
  unsigned hi = __brev(m >> 16) >> 16;       // bit i = m bit (31-i)
  lo = (lo | (lo << 8)) & 0x00FF00FFu;
  lo = (lo | (lo << 4)) & 0x0F0F0F0Fu;
  lo = (lo | (lo << 2)) & 0x33333333u;
  lo = (lo | (lo << 1)) & 0x55555555u;
  hi = (hi | (hi << 8)) & 0x00FF00FFu;
  hi = (hi | (hi << 4)) & 0x0F0F0F0Fu;
  hi = (hi | (hi << 2)) & 0x33333333u;
  hi = (hi | (hi << 1)) & 0x55555555u;
  return lo | (hi << 1);
}

#define TRANSPOSE16(B)                                                                             \
  {                                                                                                \
    unsigned t;                                                                                    \
    t = (B[0] ^ (B[8] >> 8)) & 0x00FF00FFu; B[0] ^= t; B[8] ^= (t << 8);                           \
    t = (B[1] ^ (B[9] >> 8)) & 0x00FF00FFu; B[1] ^= t; B[9] ^= (t << 8);                           \
    t = (B[2] ^ (B[10] >> 8)) & 0x00FF00FFu; B[2] ^= t; B[10] ^= (t << 8);                         \
    t = (B[3] ^ (B[11] >> 8)) & 0x00FF00FFu; B[3] ^= t; B[11] ^= (t << 8);                         \
    t = (B[4] ^ (B[12] >> 8)) & 0x00FF00FFu; B[4] ^= t; B[12] ^= (t << 8);                         \
    t = (B[5] ^ (B[13] >> 8)) & 0x00FF00FFu; B[5] ^= t; B[13] ^= (t << 8);                         \
    t = (B[6] ^ (B[14] >> 8)) & 0x00FF00FFu; B[6] ^= t; B[14] ^= (t << 8);                         \
    t = (B[7] ^ (B[15] >> 8)) & 0x00FF00FFu; B[7] ^= t; B[15] ^= (t << 8);                         \
    t = (B[0] ^ (B[4] >> 4)) & 0x0F0F0F0Fu; B[0] ^= t; B[4] ^= (t << 4);                           \
    t = (B[1] ^ (B[5] >> 4)) & 0x0F0F0F0Fu; B[1] ^= t; B[5] ^= (t << 4);                           \
    t = (B[2] ^ (B[6] >> 4)) & 0x0F0F0F0Fu; B[2] ^= t; B[6] ^= (t << 4);                           \
    t = (B[3] ^ (B[7] >> 4)) & 0x0F0F0F0Fu; B[3] ^= t; B[7] ^= (t << 4);                           \
    t = (B[8] ^ (B[12] >> 4)) & 0x0F0F0F0Fu; B[8] ^= t; B[12] ^= (t << 4);                         \
    t = (B[9] ^ (B[13] >> 4)) & 0x0F0F0F0Fu; B[9] ^= t; B[13] ^= (t << 4);                         \
    t = (B[10] ^ (B[14] >> 4)) & 0x0F0F0F0Fu; B[10] ^= t; B[14] ^= (t << 4);                       \
    t = (B[11] ^ (B[15] >> 4)) & 0x0F0F0F0Fu; B[11] ^= t; B[15] ^= (t << 4);                       \
    t = (B[0] ^ (B[2] >> 2)) & 0x33333333u; B[0] ^= t; B[2] ^= (t << 2);                           \
    t = (B[1] ^ (B[3] >> 2)) & 0x33333333u; B[1] ^= t; B[3] ^= (t << 2);                           \
    t = (B[4] ^ (B[6] >> 2)) & 0x33333333u; B[4] ^= t; B[6] ^= (t << 2);                           \
    t = (B[5] ^ (B[7] >> 2)) & 0x33333333u; B[5] ^= t; B[7] ^= (t << 2);                           \
    t = (B[8] ^ (B[10] >> 2)) & 0x33333333u; B[8] ^= t; B[10] ^= (t << 2);                         \
    t = (B[9] ^ (B[11] >> 2)) & 0x33333333u; B[9] ^= t; B[11] ^= (t << 2);                         \
    t = (B[12] ^ (B[14] >> 2)) & 0x33333333u; B[12] ^= t; B[14] ^= (t << 2);                       \
    t = (B[13] ^ (B[15] >> 2)) & 0x33333333u; B[13] ^= t; B[15] ^= (t << 2);                       \
    t = (B[0] ^ (B[1] >> 1)) & 0x55555555u; B[0] ^= t; B[1] ^= (t << 1);                           \
    t = (B[2] ^ (B[3] >> 1)) & 0x55555555u; B[2] ^= t; B[3] ^= (t << 1);                           \
    t = (B[4] ^ (B[5] >> 1)) & 0x55555555u; B[4] ^= t; B[5] ^= (t << 1);                           \
    t = (B[6] ^ (B[7] >> 1)) & 0x55555555u; B[6] ^= t; B[7] ^= (t << 1);                           \
    t = (B[8] ^ (B[9] >> 1)) & 0x55555555u; B[8] ^= t; B[9] ^= (t << 1);                           \
    t = (B[10] ^ (B[11] >> 1)) & 0x55555555u; B[10] ^= t; B[11] ^= (t << 1);                       \
    t = (B[12] ^ (B[13] >> 1)) & 0x55555555u; B[12] ^= t; B[13] ^= (t << 1);                       \
    t = (B[14] ^ (B[15] >> 1)) & 0x55555555u; B[14] ^= t; B[15] ^= (t << 1);                       \
  }

// ---------------- column-wise l2 norms (axis=1), both inputs in one launch ----------------
__global__ __launch_bounds__(128) void knorm_part(const float* __restrict__ seqs, const float* __restrict__ smis,
                                                  float* __restrict__ part_s, float* __restrict__ part_m) {
  int ls = blockIdx.x, b = blockIdx.y, t = threadIdx.x;
  const float* x; float* part; int slab;
  if (ls < 64) { x = seqs; part = part_s + (size_t)(b * 64 + ls) * 512; slab = b * 64 + ls; }
  else { x = smis; part = part_m + (size_t)(b * 4 + (ls - 64)) * 512; slab = b * 4 + (ls - 64); }
  const float* xp = x + (size_t)slab * 32 * 512 + t * 4;
  float ax = 0.f, ay = 0.f, az = 0.f, aw = 0.f;
  for (int l = 0; l < 32; ++l) {
    float4 v = *(const float4*)(xp + (size_t)l * 512);
    ax += v.x * v.x; ay += v.y * v.y; az += v.z * v.z; aw += v.w * v.w;
  }
  float4 r = {ax, ay, az, aw};
  *(float4*)(part + t * 4) = r;
}

// ---------------- merged: knorm_fin (blocks 0-63) + weight prep / bcat / zero-fills (blocks 64+) ----
__global__ __launch_bounds__(256) void kfinprep(const float* __restrict__ part_s, const float* __restrict__ part_m,
                                                float* __restrict__ nrm_s, float* __restrict__ nrm_m,
                                                const float* __restrict__ Wq, const float* __restrict__ Wk,
                                                const float* __restrict__ Wv, unsigned short* __restrict__ WT,
                                                const float* bq, const float* bk, const float* bv,
                                                float* bcat, float* log1, float* h1pre, float* h2pre) {
  __shared__ float T[32][33];
  int t = threadIdx.x;
  if (blockIdx.x < 64) {
    // ---- knorm_fin: bh0<32 seqs (NS=64), else smis (NS=4) ----
    int bh0 = blockIdx.x;
    const float* part; float* inv; int NS, bh;
    if (bh0 < 32) { part = part_s; inv = nrm_s; NS = 64; bh = bh0; }
    else { part = part_m; inv = nrm_m; NS = 4; bh = bh0 - 32; }
    int b = bh >> 1, col = (bh & 1) * 256 + t;
    float s = 0.f;
    for (int j = 0; j < NS; ++j) s += part[((size_t)(b * NS + j)) * 512 + col];
    inv[(size_t)b * 512 + col] = 1.f / fmaxf(sqrtf(s), 1e-12f);
  } else {
    int id = blockIdx.x - 64;
    int m = id >> 8, r256 = id & 255;
    if (m < 3) {
      // ---- WcatT transpose tile ----
      int ti = r256 >> 4, tj = r256 & 15;
      const float* W = m == 0 ? Wq : (m == 1 ? Wk : Wv);
      int c = t & 31, r0 = t >> 5;
#pragma unroll
      for (int j = 0; j < 4; ++j) {
        int r = r0 + j * 8;
        T[r][c] = W[(size_t)(ti * 32 + r) * 512 + tj * 32 + c];
      }
      __syncthreads();
#pragma unroll
      for (int j = 0; j < 4; ++j) {
        int r = r0 + j * 8;
        WT[(size_t)(m * 512 + tj * 32 + r) * 512 + ti * 32 + c] = f2bf(T[c][r]);
      }
    } else {
      // ---- bcat (1536) + zero log1/h1pre/h2pre ----
      int i = r256 * 256 + t;
      if (i < 1536) bcat[i] = i < 512 ? bq[i] : (i < 1024 ? bk[i - 512] : bv[i - 1024]);
      else if (i < 34304) log1[i - 1536] = 0.f;
      else if (i < 50688) h1pre[i - 34304] = 0.f;
      else if (i < 58880) h2pre[i - 50688] = 0.f;
    }
  }
}

// both casts in one launch: blocks [0,16384) seqs, [16384,17408) smis
__global__ __launch_bounds__(256) void kcast(const float* __restrict__ seqs, const float* __restrict__ smis,
                                             const float* __restrict__ nrm_s, const float* __restrict__ nrm_m,
                                             unsigned short* __restrict__ seqs_nb, unsigned short* __restrict__ smis_nb) {
  const float* x; const float* inv; unsigned short* o; int i4, shiftB;
  if (blockIdx.x < 16384) {
    i4 = (blockIdx.x * 256 + threadIdx.x) * 4; x = seqs; inv = nrm_s; o = seqs_nb; shiftB = 20;
  } else {
    i4 = ((blockIdx.x - 16384) * 256 + threadIdx.x) * 4; x = smis; inv = nrm_m; o = smis_nb; shiftB = 16;
  }
  int b = i4 >> shiftB;
  float4 v = *(const float4*)(x + i4);
  float4 nv = *(const float4*)(inv + (b << 9) + (i4 & 511));
  ushort4 r;
  r.x = f2bf(v.x * nv.x); r.y = f2bf(v.y * nv.y);
  r.z = f2bf(v.z * nv.z); r.w = f2bf(v.w * nv.w);
  *(ushort4*)(o + i4) = r;
}

// ---------------- bf16 MFMA GEMM: C[M,N] = A[M,K] @ Bt[N,K]^T + bias ----------------
// v3 + merged big/small dispatch. LDS dbuf (1 barrier/K-iter) + XCD remap. Single dispatch.
__global__ __launch_bounds__(256) void kgemm(const unsigned short* __restrict__ A1,
                                             const unsigned short* __restrict__ A2,
                                             const unsigned short* __restrict__ Bt,
                                             const float* __restrict__ bias,
                                             unsigned short* __restrict__ C1,
                                             unsigned short* __restrict__ C2) {
  const int K = 512, N = NC, NT = 12;
  __shared__ unsigned short As[2][128 * 32], Bs[2][128 * 32];
  int tid = threadIdx.x, lane = tid & 63, wave = tid >> 6;
  int id = blockIdx.x;
  const unsigned short* A; unsigned short* C;
  if (id < 3072) { A = A1; C = C1; }
  else { A = A2; C = C2; id -= 3072; }
  int xcd = id & 7, j = id >> 3;
  int mloc = j / NT, n = j - mloc * NT;
  int m0 = (mloc * 8 + xcd) * 128, n0 = n * 128;
  f32x4 acc[4][4] = {};
  int wm = (wave >> 1) * 64, wn = (wave & 1) * 64;
  int frow = lane & 15, fk = (lane >> 4) * 8;

  auto stage = [&](int buf, int k0) {
#pragma unroll
    for (int jj = 0; jj < 2; ++jj) {
      int ch = jj * 256 + tid;
      int row = ch >> 2, kc = (ch & 3) * 8;
      gld16(A + (size_t)(m0 + row) * K + k0 + kc, As[buf] + ch * 8);
      gld16(Bt + (size_t)(n0 + row) * K + k0 + kc, Bs[buf] + ch * 8);
    }
  };

  stage(0, 0);
  __syncthreads();
  int nk = K >> 5;
  for (int it = 0; it < nk; ++it) {
    int cur = it & 1;
    if (it + 1 < nk) stage(cur ^ 1, (it + 1) << 5);
    bf16x8 af[4], bfv[4];
#pragma unroll
    for (int mt = 0; mt < 4; ++mt) af[mt] = *(const bf16x8*)&As[cur][(wm + mt * 16 + frow) * 32 + fk];
#pragma unroll
    for (int nt = 0; nt < 4; ++nt) bfv[nt] = *(const bf16x8*)&Bs[cur][(wn + nt * 16 + frow) * 32 + fk];
#pragma unroll
    for (int mt = 0; mt < 4; ++mt)
#pragma unroll
      for (int nt = 0; nt < 4; ++nt)
        acc[mt][nt] = __builtin_amdgcn_mfma_f32_16x16x32_bf16(af[mt], bfv[nt], acc[mt][nt], 0, 0, 0);
    __syncthreads();
  }
  int q = lane >> 4, c15 = lane & 15;
#pragma unroll
  for (int mt = 0; mt < 4; ++mt)
#pragma unroll
    for (int nt = 0; nt < 4; ++nt) {
      int col = n0 + wn + nt * 16 + c15;
      float bv = bias[col];
#pragma unroll
      for (int r = 0; r < 4; ++r) {
        int row = m0 + wm + mt * 16 + q * 4 + r;
        C[(size_t)row * N + col] = f2bf(acc[mt][nt][r] + bv);
      }
    }
}

// ---------------- fusion 1: Q=seqs(2048) K,V=smis(128); top-32 of 128 ----------------
// v5 dense writeback (R5 lesson: divergent sparse while-loop regressed). Single dispatch.
__global__ __launch_bounds__(256) void kfusion1(const unsigned short* __restrict__ Pseqs,
                                                const unsigned short* __restrict__ Psmis,
                                                const float* __restrict__ wp,
                                                unsigned short* __restrict__ smil,
                                                float* __restrict__ logits) {
  constexpr int PP = 136;                 // halfword pitch, rows 16B-aligned
  __shared__ unsigned short Sc[64 * PP];  // scores, then unnormalized P (bf16)
  __shared__ unsigned short Vt[64 * PP];  // V^T [e][s ^ (e&56)] (swizzled)
  int tid = threadIdx.x, lane = tid & 63, w = tid >> 6;
  int lt = blockIdx.x, h = blockIdx.y, b = blockIdx.z;
  int l0 = lt * 64;
  int frow = lane & 15, q = lane >> 4, fk8 = q * 8;

  // stage V^T, XOR swizzle on s-blocks
  for (int ch = tid; ch < 1024; ch += 256) {
    int s = ch >> 3, e8 = (ch & 7) * 8;
    u16x8 vv = *(const u16x8*)&Psmis[(size_t)(b * 128 + s) * NC + 1024 + h * 64 + e8];
#pragma unroll
    for (int j = 0; j < 8; ++j) {
      int e = e8 + j;
      Vt[e * PP + (s ^ (e & 56))] = vv[j];
    }
  }

  // scores: wave w's 16 Q-rows x 128 keys, fragments from global (L2-hot)
  {
    f32x4 acc[8] = {};
    const unsigned short* qrow = Pseqs + (size_t)(b * 2048 + l0 + w * 16 + frow) * NC + h * 64 + fk8;
#pragma unroll
    for (int ks = 0; ks < 2; ++ks) {
      bf16x8 a = *(const bf16x8*)(qrow + ks * 32);
#pragma unroll
      for (int nt = 0; nt < 8; ++nt) {
        bf16x8 bb = *(const bf16x8*)&Psmis[(size_t)(b * 128 + nt * 16 + frow) * NC + 512 + h * 64 + ks * 32 + fk8];
        acc[nt] = __builtin_amdgcn_mfma_f32_16x16x32_bf16(a, bb, acc[nt], 0, 0, 0);
      }
    }
#pragma unroll
    for (int nt = 0; nt < 8; ++nt)
#pragma unroll
      for (int r = 0; r < 4; ++r)
        Sc[(w * 16 + q * 4 + r) * PP + nt * 16 + frow] = f2bf(acc[nt][r]);
  }
  __syncthreads();

  // selection: lane owns 32 cols (seg = lane&3) of row (lane>>2); 16 rows per wave in one pass
  {
    int i = lane >> 2, seg = lane & 3;
    int row = w * 16 + i;
    unsigned short* rb = &Sc[row * PP + seg * 32];
    unsigned orig[16], B[16];
#pragma unroll
    for (int jb = 0; jb < 4; ++jb) {
      uint4 qv = *(const uint4*)(rb + jb * 8);
      orig[jb * 4 + 0] = qv.x; orig[jb * 4 + 1] = qv.y;
      orig[jb * 4 + 2] = qv.z; orig[jb * 4 + 3] = qv.w;
    }
#pragma unroll
    for (int j = 0; j < 16; ++j) {
      unsigned s = (orig[j] >> 15) & 0x00010001u;
      B[j] = orig[j] ^ (s * 0x7FFFu) ^ 0x80008000u;
    }
    TRANSPOSE16(B)
    unsigned act = 0xFFFFFFFFu, gt = 0u, Tv = 0u;
    int rem = 32;
#pragma unroll
    for (int bit = 15; bit >= 0; --bit) {
      unsigned bm = B[15 - bit] & act;
      int c = __popc(bm);
      c += __shfl_xor(c, 1);
      c += __shfl_xor(c, 2);
      bool take = (c >= rem);
      act = take ? bm : (act ^ bm);
      gt = take ? gt : (gt | bm);
      rem = take ? rem : (rem - c);
      Tv = take ? (Tv | (1u << bit)) : Tv;
    }
    unsigned hT = (Tv & 0x8000u) ? (Tv ^ 0x8000u) : (Tv ^ 0xFFFFu);
    float vT = bf2f((unsigned short)hT);
    unsigned gtE = pos2elem(gt), actE = pos2elem(act);
    int pc = __popc(actE);
    int pr1 = __shfl_up(pc, 1);
    int inc = pc + ((seg >= 1) ? pr1 : 0);
    int pr2 = __shfl_up(inc, 2);
    inc += ((seg >= 2) ? pr2 : 0);
    int tie_pre = inc - pc;
    int budget = rem - tie_pre;
    budget = budget < 0 ? 0 : (budget > pc ? pc : budget);
    unsigned selT = 0u, m = actE;
    for (int t = 0; t < budget; ++t) { unsigned bb2 = m & (~m + 1u); selT |= bb2; m ^= bb2; }
    unsigned sel = gtE | selT;
    unsigned* wb = (unsigned*)rb;
#pragma unroll
    for (int j = 0; j < 16; ++j) {
      unsigned d = orig[j];
      float v0 = bf2f((unsigned short)(d & 0xFFFFu));
      float v1 = bf2f((unsigned short)(d >> 16));
      float e0 = ((sel >> (2 * j)) & 1u) ? __expf((v0 - vT) * 0.125f) : 0.f;
      float e1 = ((sel >> (2 * j + 1)) & 1u) ? __expf((v1 - vT) * 0.125f) : 0.f;
      wb[j] = (unsigned)f2bf(e0) | ((unsigned)f2bf(e1) << 16);
    }
  }
  __syncthreads();

  // O_un = P_un[16x128] @ V[128x64]; den = P_un @ ones (extra MFMA column)
  f32x4 oacc[4] = {};
  f32x4 dacc = {};
  bf16x8 ones;
#pragma unroll
  for (int j = 0; j < 8; ++j) ones[j] = (__bf16)1.0f;
#pragma unroll
  for (int k0 = 0; k0 < 128; k0 += 32) {
    bf16x8 a = *(const bf16x8*)&Sc[(w * 16 + frow) * PP + k0 + fk8];
#pragma unroll
    for (int nt = 0; nt < 4; ++nt) {
      int e = nt * 16 + frow;
      bf16x8 bb = *(const bf16x8*)&Vt[e * PP + ((k0 + fk8) ^ (e & 56))];
      oacc[nt] = __builtin_amdgcn_mfma_f32_16x16x32_bf16(a, bb, oacc[nt], 0, 0, 0);
    }
    dacc = __builtin_amdgcn_mfma_f32_16x16x32_bf16(a, ones, dacc, 0, 0, 0);
  }
  float inv4[4];
#pragma unroll
  for (int r = 0; r < 4; ++r) inv4[r] = 1.f / dacc[r];
  // write O and accumulate pool-1 logit partials
  float wv[4];
#pragma unroll
  for (int nt = 0; nt < 4; ++nt) wv[nt] = wp[h * 64 + nt * 16 + frow];
  float lg[4];
#pragma unroll
  for (int r = 0; r < 4; ++r) lg[r] = 0.f;
#pragma unroll
  for (int nt = 0; nt < 4; ++nt)
#pragma unroll
    for (int r = 0; r < 4; ++r) {
      float ov = oacc[nt][r] * inv4[r];
      smil[(size_t)(b * 2048 + l0 + w * 16 + q * 4 + r) * 512 + h * 64 + nt * 16 + frow] = f2bf(ov);
      lg[r] += ov * wv[nt];
    }
#pragma unroll
  for (int d = 1; d < 16; d <<= 1)
#pragma unroll
    for (int r = 0; r < 4; ++r) lg[r] += __shfl_xor(lg[r], d);
  if (frow == 0) {
#pragma unroll
    for (int r = 0; r < 4; ++r)
      atomicAdd(&logits[b * 2048 + l0 + w * 16 + q * 4 + r], lg[r]);
  }
}

// ---------------- fusion 2 + pool1b MERGED (kept from R9; head coop reverted) ----------------
// Blocks [0,1024): kf2fused v3 (flattened grid, bh-major preserved: bh=bid&127, rt=bid>>7).
// Blocks [1024,1280): kpool1b rewritten for 1024 threads; scratch aliased into S.
__global__ __launch_bounds__(1024, 8) void kf2pool(const unsigned short* __restrict__ Psmis,
                                                   const unsigned short* __restrict__ Pseqs,
                                                   float* __restrict__ seqs_out,
                                                   const unsigned short* __restrict__ xsm,
                                                   const float* __restrict__ logits,
                                                   float* __restrict__ aout, float* __restrict__ pp) {
  __shared__ unsigned short S[16 * 2048];  // 64 KB: bf16 scores (kf2) / float scratch (pool1b)
  __shared__ float pS[16][32];
  __shared__ int   sS[16][32];
  int tid = threadIdx.x, lane = tid & 63, w = tid >> 6;  // w in 0..15

  if (blockIdx.x >= 1024) {
    // ======== pool1b path (256 blocks, 1024 threads) ========
    int bid = blockIdx.x - 1024;
    int b = bid >> 4, ls = (bid >> 1) & 7, cj = bid & 1;
    float* redf = (float*)S;           // 1024 floats, bytes [0,4096)
    float* aSf = (float*)(S + 2048);   // 256 floats, bytes [4096,5120)
    const float* lg = logits + b * 2048;
    int t = tid;
    float lm = fmaxf(lg[t], lg[t + 1024]);
    redf[t] = lm; __syncthreads();
    for (int s = 512; s > 0; s >>= 1) { if (t < s) redf[t] = fmaxf(redf[t], redf[t + s]); __syncthreads(); }
    float M = redf[0]; __syncthreads();
    float sm = __expf(lg[t] - M) + __expf(lg[t + 1024] - M);
    redf[t] = sm; __syncthreads();
    for (int s = 512; s > 0; s >>= 1) { if (t < s) redf[t] += redf[t + s]; __syncthreads(); }
    float D = redf[0]; __syncthreads();
    int l0 = ls * 256;
    int tc = t & 255, g = t >> 8;
    if (g == 0) {
      float a = __expf(lg[l0 + tc] - M) / D;
      aSf[tc] = a;
      if (cj == 0) aout[b * 2048 + l0 + tc] = a;
    }
    __syncthreads();
    int col = cj * 256 + tc;
    float acc0 = 0.f;
    const unsigned short* xb = xsm + ((size_t)b * 2048 + l0 + g * 64) * 512 + col;
#pragma unroll 8
    for (int ll = 0; ll < 64; ++ll) acc0 += aSf[g * 64 + ll] * bf2f(xb[(size_t)ll * 512]);
    redf[t] = acc0; __syncthreads();
    if (g == 0)
      pp[(size_t)(b * 8 + ls) * 512 + col] = redf[tc] + redf[256 + tc] + redf[512 + tc] + redf[768 + tc];
    return;
  }

  // ======== kf2fused path (1024 blocks) ========
  int bh = blockIdx.x & 127, rt = blockIdx.x >> 7;
  int b = bh >> 3, h = bh & 7;
  int frow = lane & 15, q = lane >> 4, fk8 = q * 8;

  // ---- scores: rows l = rt*16..+15 (smis queries); wave w covers s in [w*128,(w+1)*128) ----
  {
    const unsigned short* qrow = Psmis + (size_t)(b * 128 + rt * 16 + frow) * NC + h * 64 + fk8;
    bf16x8 a0 = *(const bf16x8*)qrow;
    bf16x8 a1 = *(const bf16x8*)(qrow + 32);
    const unsigned short* Bb = Pseqs + (size_t)(b * 2048) * NC + 512 + h * 64 + fk8;
#pragma unroll
    for (int nt = 0; nt < 8; ++nt) {
      int n0 = w * 128 + nt * 16;
      const unsigned short* brow = Bb + (size_t)(n0 + frow) * NC;
      bf16x8 b0 = *(const bf16x8*)brow;
      bf16x8 b1 = *(const bf16x8*)(brow + 32);
      f32x4 acc = {};
      acc = __builtin_amdgcn_mfma_f32_16x16x32_bf16(a0, b0, acc, 0, 0, 0);
      acc = __builtin_amdgcn_mfma_f32_16x16x32_bf16(a1, b1, acc, 0, 0, 0);
      int el = n0 + frow;
      int cc = el >> 3;
      int base = cc ^ ((cc >> 3) & 7);
#pragma unroll
      for (int r = 0; r < 4; ++r) {
        int row = q * 4 + r;
        S[row * 2048 + ((base ^ (row & 7)) << 3) + (el & 7)] = f2bf(acc[r]);
      }
    }
  }
  __syncthreads();

  // ---- per-wave selection: wave w owns row w ----
  int lr = w, x = w & 7;

  unsigned B[16];
  {
    const uint4* p4 = (const uint4*)&S[lr * 2048];
#pragma unroll
    for (int i = 0; i < 4; ++i) {
      int cc = lane * 4 + i;
      int base = cc ^ ((cc >> 3) & 7);
      uint4 qa = p4[base ^ x];
      B[i * 4 + 0] = qa.x; B[i * 4 + 1] = qa.y; B[i * 4 + 2] = qa.z; B[i * 4 + 3] = qa.w;
    }
  }
#pragma unroll
  for (int i = 0; i < 16; ++i) {
    unsigned s0 = (B[i] >> 15) & 0x00010001u;
    B[i] = B[i] ^ (s0 * 0x7FFFu) ^ 0x80008000u;
  }
  TRANSPOSE16(B)
  unsigned act = 0xFFFFFFFFu, gt = 0u, Tv = 0u;
  int rem = 32;
#pragma unroll
  for (int bit = 15; bit >= 0; --bit) {
    unsigned bm = B[15 - bit] & act;
    int c = __popc(bm);
#pragma unroll
    for (int d = 1; d < 64; d <<= 1) c += __shfl_xor(c, d);
    bool take = (c >= rem);
    unsigned actx = act ^ bm;
    act = take ? bm : actx;
    gt = take ? gt : (gt | bm);
    rem = take ? rem : (rem - c);
    Tv = take ? (Tv | (1u << bit)) : Tv;
  }
  unsigned hT = (Tv & 0x8000u) ? (Tv ^ 0x8000u) : (Tv ^ 0xFFFFu);
  float vT = bf2f((unsigned short)hT);

  gt = pos2elem(gt);
  act = pos2elem(act);

  int pc_tie = __popc(act);
  int inc = pc_tie;
#pragma unroll
  for (int d = 1; d < 64; d <<= 1) { int y = __shfl_up(inc, d); if (lane >= d) inc += y; }
  int tie_pre = inc - pc_tie;
  int budget = rem - tie_pre;
  budget = budget < 0 ? 0 : (budget > pc_tie ? pc_tie : budget);
  int total_lane = __popc(gt) + budget;
  int inc2 = total_lane;
#pragma unroll
  for (int d = 1; d < 64; d <<= 1) { int y = __shfl_up(inc2, d); if (lane >= d) inc2 += y; }
  int slot = inc2 - total_lane;

  float lsum = 0.f;
  {
    unsigned m = gt;
    while (m) {
      int e = __builtin_ctz(m); m &= m - 1;
      int gidx = (lane << 5) + e;
      int cc = gidx >> 3;
      float v = bf2f(S[lr * 2048 + (((cc ^ ((cc >> 3) & 7)) ^ x) << 3) + (gidx & 7)]);
      float ev = __expf((v - vT) * 0.125f);
      pS[lr][slot] = ev; sS[lr][slot] = gidx; ++slot; lsum += ev;
    }
    m = act;
    for (int taken = 0; taken < budget; ++taken) {
      int e = __builtin_ctz(m); m &= m - 1;
      int gidx = (lane << 5) + e;
      int cc = gidx >> 3;
      float v = bf2f(S[lr * 2048 + (((cc ^ ((cc >> 3) & 7)) ^ x) << 3) + (gidx & 7)]);
      float ev = __expf((v - vT) * 0.125f);
      pS[lr][slot] = ev; sS[lr][slot] = gidx; ++slot; lsum += ev;
    }
  }
  float den = lsum;
#pragma unroll
  for (int d = 1; d < 64; d <<= 1) den += __shfl_xor(den, d);

  // ---- PV gather ----
  float acc = 0.f;
  const unsigned short* Vb = Pseqs + (size_t)(b * 2048) * NC + 1024 + h * 64 + lane;
#pragma unroll 8
  for (int t = 0; t < 32; ++t) {
    acc += pS[lr][t] * bf2f(Vb[(size_t)sS[lr][t] * NC]);
  }
  seqs_out[(size_t)(b * 128 + rt * 16 + lr) * 512 + h * 64 + lane] = acc / den;
}

// ---------------- pool 2 + emb (fused): per-b softmax pool over seqs_out, concat, l2-norm ----------------
// R10: restored plain-dispatch head (R9 coop grid.sync cost ~45-60us each -- 184us kernel).
__global__ __launch_bounds__(256) void kpool2emb(const float* __restrict__ x,
                                                 const float* __restrict__ wp, const float* __restrict__ bp,
                                                 const float* __restrict__ pp,
                                                 float* __restrict__ a2out, float* __restrict__ embo) {
  __shared__ float lgS[128];
  __shared__ float red[256];
  int t = threadIdx.x, lane = t & 63, wave = t >> 6;
  int b = blockIdx.x;
  for (int i = 0; i < 32; ++i) {
    int row = wave * 32 + i;
    const float* xp = x + (size_t)(b * 128 + row) * 512;
    float acc = 0.f;
#pragma unroll
    for (int j = 0; j < 8; ++j) acc += xp[lane + 64 * j] * wp[lane + 64 * j];
#pragma unroll
    for (int d = 1; d < 64; d <<= 1) acc += __shfl_xor(acc, d);
    if (lane == 0) lgS[row] = acc + bp[0];
  }
  __syncthreads();
  if (wave == 0) {
    float a0 = lgS[lane], a1 = lgS[64 + lane];
    float m = fmaxf(a0, a1);
#pragma unroll
    for (int d = 1; d < 64; d <<= 1) m = fmaxf(m, __shfl_xor(m, d));
    float e0 = __expf(a0 - m), e1 = __expf(a1 - m);
    float sden = e0 + e1;
#pragma unroll
    for (int d = 1; d < 64; d <<= 1) sden += __shfl_xor(sden, d);
    a0 = e0 / sden; a1 = e1 / sden;
    lgS[lane] = a0; lgS[64 + lane] = a1;
    a2out[b * 128 + lane] = a0;
    a2out[b * 128 + 64 + lane] = a1;
  }
  __syncthreads();
  float acc0 = 0.f, acc1 = 0.f;
#pragma unroll 4
  for (int row = 0; row < 128; ++row) {
    float av = lgS[row];
    const float* xp = x + (size_t)(b * 128 + row) * 512;
    acc0 += av * xp[t];
    acc1 += av * xp[t + 256];
  }
  // emb: cols t, 256+t from pp sums; 512+t = acc0; 768+t = acc1
  float pre0 = 0.f, pre1 = 0.f;
  for (int lsl = 0; lsl < 8; ++lsl) {
    pre0 += pp[(size_t)(b * 8 + lsl) * 512 + t];
    pre1 += pp[(size_t)(b * 8 + lsl) * 512 + 256 + t];
  }
  float ssq = pre0 * pre0 + pre1 * pre1 + acc0 * acc0 + acc1 * acc1;
  red[t] = ssq; __syncthreads();
  for (int s2 = 128; s2 > 0; s2 >>= 1) { if (t < s2) red[t] += red[t + s2]; __syncthreads(); }
  float inv = 1.f / fmaxf(sqrtf(red[0]), 1e-12f);
  embo[(size_t)b * 1024 + t] = pre0 * inv;
  embo[(size_t)b * 1024 + 256 + t] = pre1 * inv;
  embo[(size_t)b * 1024 + 512 + t] = acc0 * inv;
  embo[(size_t)b * 1024 + 768 + t] = acc1 * inv;
}

// ---------------- head: split-K parallel MLP (plain dispatches) ----------------
__global__ __launch_bounds__(256) void kh1(const float* __restrict__ emb, const float* __restrict__ W1,
                                           float* __restrict__ h1pre) {
  __shared__ float eS[4][64];
  int t = threadIdx.x;
  int jc = blockIdx.x, bg = blockIdx.y, kc = blockIdx.z;
  int j = jc * 256 + t, b0 = bg * 4, i0 = kc * 64;
  eS[t >> 6][t & 63] = emb[(size_t)(b0 + (t >> 6)) * 1024 + i0 + (t & 63)];
  __syncthreads();
  float a0 = 0.f, a1 = 0.f, a2 = 0.f, a3 = 0.f;
#pragma unroll 8
  for (int i = 0; i < 64; ++i) {
    float w = W1[(size_t)(i0 + i) * 1024 + j];
    a0 += eS[0][i] * w; a1 += eS[1][i] * w; a2 += eS[2][i] * w; a3 += eS[3][i] * w;
  }
  atomicAdd(&h1pre[(b0 + 0) * 1024 + j], a0);
  atomicAdd(&h1pre[(b0 + 1) * 1024 + j], a1);
  atomicAdd(&h1pre[(b0 + 2) * 1024 + j], a2);
  atomicAdd(&h1pre[(b0 + 3) * 1024 + j], a3);
}

__global__ __launch_bounds__(256) void kh2(const float* __restrict__ h1pre, const float* __restrict__ b1,
                                           const float* __restrict__ W2, float* __restrict__ h2pre) {
  __shared__ float eS[4][64];
  int t = threadIdx.x;
  int jc = blockIdx.x, bg = blockIdx.y, kc = blockIdx.z;
  int j = jc * 256 + t, b0 = bg * 4, i0 = kc * 64;
  eS[t >> 6][t & 63] = fmaxf(h1pre[(size_t)(b0 + (t >> 6)) * 1024 + i0 + (t & 63)] + b1[i0 + (t & 63)], 0.f);
  __syncthreads();
  float a0 = 0.f, a1 = 0.f, a2 = 0.f, a3 = 0.f;
#pragma unroll 8
  for (int i = 0; i < 64; ++i) {
    float w = W2[(size_t)(i0 + i) * 512 + j];
    a0 += eS[0][i] * w; a1 += eS[1][i] * w; a2 += eS[2][i] * w; a3 += eS[3][i] * w;
  }
  atomicAdd(&h2pre[(b0 + 0) * 512 + j], a0);
  atomicAdd(&h2pre[(b0 + 1) * 512 + j], a1);
  atomicAdd(&h2pre[(b0 + 2) * 512 + j], a2);
  atomicAdd(&h2pre[(b0 + 3) * 512 + j], a3);
}

// kout: out[b] = relu(h2pre+b2) . W3 + b3; grid 16
__global__ __launch_bounds__(256) void kout(const float* __restrict__ h2pre, const float* __restrict__ b2,
                                            const float* __restrict__ W3, const float* __restrict__ b3,
                                            float* __restrict__ outp) {
  __shared__ float red[256];
  int t = threadIdx.x, b = blockIdx.x;
  float acc = 0.f;
  for (int j = t; j < 512; j += 256)
    acc += fmaxf(h2pre[b * 512 + j] + b2[j], 0.f) * W3[j];
  red[t] = acc; __syncthreads();
  for (int s = 128; s > 0; s >>= 1) { if (t < s) red[t] += red[t + s]; __syncthreads(); }
  if (t == 0) outp[b] = red[0] + b3[0];
}

// ---------------- launch ----------------
extern "C" void kernel_launch(void* const* d_in, const int* in_sizes, int n_in,
                              void* d_out, int out_size, void* d_ws, size_t ws_size,
                              hipStream_t stream) {
  const float* seqs = (const float*)d_in[0];
  const float* smis = (const float*)d_in[1];
  const float* Wq = (const float*)d_in[2];
  const float* bq = (const float*)d_in[3];
  const float* Wk = (const float*)d_in[4];
  const float* bk = (const float*)d_in[5];
  const float* Wv = (const float*)d_in[6];
  const float* bv = (const float*)d_in[7];
  const float* wp = (const float*)d_in[8];
  const float* bp = (const float*)d_in[9];
  const float* W1 = (const float*)d_in[10];
  const float* b1 = (const float*)d_in[11];
  const float* W2 = (const float*)d_in[12];
  const float* b2 = (const float*)d_in[13];
  const float* W3 = (const float*)d_in[14];
  const float* b3 = (const float*)d_in[15];
  float* out = (float*)d_out;
  char* ws = (char*)d_ws;

  float* nrm_s = (float*)(ws + WS_NRM_S);
  float* nrm_m = (float*)(ws + WS_NRM_M);
  float* part_s = (float*)(ws + WS_PART);
  float* part_m = (float*)(ws + WS_PARTM);
  float* bcat = (float*)(ws + WS_BCAT);
  float* log1 = (float*)(ws + WS_LOG1);
  float* pp1 = (float*)(ws + WS_PP1);
  float* h1pre = (float*)(ws + WS_H1);
  float* h2pre = (float*)(ws + WS_H2);
  unsigned short* wct = (unsigned short*)(ws + WS_WCT);
  unsigned short* smis_nb = (unsigned short*)(ws + WS_SMISNB);
  unsigned short* Psmis = (unsigned short*)(ws + WS_PSMIS);
  float* seqs_out = (float*)(ws + WS_SEQSOUT);
  unsigned short* seqs_nb = (unsigned short*)(ws + WS_SEQSNB);
  unsigned short* Pseqs = (unsigned short*)(ws + WS_PSEQS);
  unsigned short* smil = (unsigned short*)(ws + WS_SMILOUT);

  // 1. column norms (part buffers alias Pseqs region; consumed before kgemm writes it)
  knorm_part<<<dim3(68, 16), 128, 0, stream>>>(seqs, smis, part_s, part_m);
  // 2. norm finalize + weight prep + bcat + zero-fills (merged)
  kfinprep<<<dim3(1088), 256, 0, stream>>>(part_s, part_m, nrm_s, nrm_m,
                                           Wq, Wk, Wv, wct, bq, bk, bv, bcat, log1, h1pre, h2pre);
  // 3. normalize + cast to bf16 (both inputs)
  kcast<<<dim3(17408), 256, 0, stream>>>(seqs, smis, nrm_s, nrm_m, seqs_nb, smis_nb);
  // 4. fused QKV projections
  kgemm<<<dim3(3264), 256, 0, stream>>>(seqs_nb, smis_nb, wct, bcat, Pseqs, Psmis);
  // 5. fusion 1 attention + fused pool-1 logits
  kfusion1<<<dim3(32, 8, 16), 256, 0, stream>>>(Pseqs, Psmis, wp, smil, log1);
  // 6. fusion 2 + pool 1 merged (disjoint deps -> concurrent in one dispatch)
  kf2pool<<<dim3(1280), 1024, 0, stream>>>(Psmis, Pseqs, seqs_out, smil, log1, out + OUT_A1, pp1);
  // 7-8. head: plain dispatches (R9 lesson: grid.sync ~45-60us each on MI355X -- coop launch
  //      for tiny-kernel chains is a large net loss)
  kpool2emb<<<dim3(16), 256, 0, stream>>>(seqs_out, wp, bp, pp1, out + OUT_A2, out + OUT_EMB);
  kh1<<<dim3(4, 4, 16), 256, 0, stream>>>(out + OUT_EMB, W1, h1pre);
  kh2<<<dim3(2, 4, 16), 256, 0, stream>>>(h1pre, b1, W2, h2pre);
  kout<<<dim3(16), 256, 0, stream>>>(h2pre, b2, W3, b3, out + OUT_OUT);
}